// Round 5
// baseline (8374.409 us; speedup 1.0000x reference)
//
#include <hip/hip_runtime.h>
#include <stdint.h>
#include <stddef.h>

#define DEV __device__ __forceinline__

// ---------------- workspace offsets (bytes) ----------------
#define OFF_PRM     8192u
#define OFF_DIS     12288u
#define OFF_RW1T    12800u
#define OFF_RW3T    20992u
#define OFF_LINT    29184u
#define OFF_WT      45568u      // conv weights transposed: [(ic*3+k)*256 + c], 768KB
#define OFF_PRE     1618432u    // preact 32MB; E (32MB) aliases this after lifA
#define OFF_MASKA   35172864u
#define OFF_MASKO4  36221440u
#define OFF_CMAX    36483584u
#define OFF_CSUM    36614656u
#define OFF_SUP1    36745728u
#define OFF_RES1    40940032u
#define OFF_SUP3    45134336u
#define OFF_RES3    49328640u
#define OFF_X1H     53522944u
#define OFF_X2H     53654016u
#define OFF_X1M     53785088u
#define OFF_X2M     53916160u
#define OFF_GPRE    54047232u
#define OFF_MSG     62435840u   // tim msgs: [t][ch] qword = (tag<<32)|batchmask, 2MB

// Correctly-rounded a/1.6f (Markstein: y = RN(1/1.6f) = 0.625f).
// Bit-identical to IEEE divide; chain = mul+fma+fma instead of ~7-op div seq.
DEV float div16(float a) {
  const float c = 1.6f, y = 0.625f;
  float q0 = a * y;
  float e  = fmaf(-c, q0, a);
  return fmaf(e, y, q0);
}
DEV float lif_step(float v, float x) { return v + div16(x - v); }

// ---------------- prep: weight transposes / BN params / dis table ----------------
__global__ void prep_kernel(
    const float* __restrict__ convs_w, const float* __restrict__ convs_b,
    const float* __restrict__ bn_g, const float* __restrict__ bn_b,
    const float* __restrict__ bn_m, const float* __restrict__ bn_v,
    const float* __restrict__ conv4_w,
    const float* __restrict__ gc1_res_w, const float* __restrict__ gc3_res_w,
    const float* __restrict__ lin_w,
    float* __restrict__ wT, float* __restrict__ prm, float* __restrict__ dis,
    float* __restrict__ rw1T, float* __restrict__ rw3T, float* __restrict__ linT)
{
  int gid = blockIdx.x*256 + threadIdx.x;
  if (gid < 196608) {                      // wT[(ic*3+k)*256 + c]
    int c = gid & 255, kc = gid >> 8;
    int ic = kc/3, k = kc - ic*3;
    float v;
    if (c < 192) { int i = c>>6, oc = c&63; v = convs_w[((i*64+oc)*256 + ic)*3 + k]; }
    else         { v = (k==1) ? conv4_w[(c-192)*256 + ic] : 0.f; }
    wT[gid] = v; return;
  }
  gid -= 196608;
  if (gid < 1024) {                        // prm: bias/mean/scale/beta
    int c = gid & 255, which = gid >> 8;
    float v;
    if (c < 192) {
      int idx = (c>>6)*64 + (c&63);
      if (which==0) v = convs_b[idx];
      else if (which==1) v = bn_m[idx];
      else if (which==2) v = bn_g[idx] / sqrtf(bn_v[idx] + 1e-5f);
      else v = bn_b[idx];
    } else v = (which==2) ? 1.f : 0.f;
    prm[which*256 + c] = v; return;
  }
  gid -= 1024;
  if (gid < 2048) { int i = gid>>5, j = gid&31; rw1T[gid] = gc1_res_w[j*64 + i]; return; }
  gid -= 2048;
  if (gid < 2048) { int i = gid>>5, j = gid&31; rw3T[gid] = gc3_res_w[j*64 + i]; return; }
  gid -= 2048;
  if (gid < 4096) { int i = gid>>6, c = gid&63; linT[gid] = lin_w[c*64 + i]; return; }
  gid -= 4096;
  if (gid < 128) { dis[gid] = expf(-(float)gid / 2.7182817459106445f); return; }
}

// ---------------- K1: fused dilated-conv pyramid + conv4 (+BN), fp32 ----------------
__global__ __launch_bounds__(256) void conv_kernel(
    const float* __restrict__ x, const float* __restrict__ wT,
    const float* __restrict__ prm, float* __restrict__ preact)
{
  __shared__ float xs[72][130];
  int b = blockIdx.y, t0 = blockIdx.x*64;
  int tid = threadIdx.x;
  int wv = tid>>6, l = tid&63;
  int dil = (wv==1) ? 2 : ((wv==2) ? 4 : 1);
  const float* bias = prm; const float* mean = prm+256;
  const float* scale = prm+512; const float* beta = prm+768;
  for (int p = 0; p < 2; ++p) {
    int cbase = __builtin_amdgcn_readfirstlane(wv*64 + p*32);
    float acc[32];
    #pragma unroll
    for (int u=0;u<32;++u) acc[u]=0.f;
    for (int icc = 0; icc < 2; ++icc) {
      __syncthreads();
      for (int r = wv; r < 72; r += 4) {
        int tt = t0 - 4 + r;
        float2 v = make_float2(0.f, 0.f);
        if (tt >= 0 && tt < 1024)
          v = *(const float2*)(x + ((size_t)b*1024 + tt)*256 + icc*128 + l*2);
        xs[r][l*2] = v.x; xs[r][l*2+1] = v.y;
      }
      __syncthreads();
      for (int ic = 0; ic < 128; ++ic) {
        float xm = xs[4 + l - dil][ic];
        float x0 = xs[4 + l][ic];
        float xp = xs[4 + l + dil][ic];
        const float* w0 = wT + (size_t)((icc*128+ic)*3)*256 + cbase;
        const float* w1 = w0 + 256; const float* w2 = w0 + 512;
        #pragma unroll
        for (int u=0;u<32;++u)
          acc[u] = fmaf(w0[u], xm, fmaf(w1[u], x0, fmaf(w2[u], xp, acc[u])));
      }
    }
    #pragma unroll
    for (int u=0;u<32;++u) {
      int c = cbase + u;
      float o = acc[u] + bias[c];
      o = (o - mean[c])*scale[c] + beta[c];
      preact[((size_t)b*256 + c)*1024 + t0 + l] = o;
    }
  }
}

// ---------------- K2: LIF over T for 256 channels -> bitmasks ----------------
__global__ void lifA_kernel(const float* __restrict__ preact,
                            uint64_t* __restrict__ maskA, uint64_t* __restrict__ maskO4)
{
  int b = blockIdx.x, cg = threadIdx.x>>6, lane = threadIdx.x&63;
  int c = cg*64 + lane;
  const float* p = preact + ((size_t)b*256 + c)*1024;
  float v = 0.f;
  #pragma unroll 4
  for (int t = 0; t < 1024; ++t) {
    float xv = p[t];
    v = lif_step(v, xv);
    bool s = (v - 1.0f) >= 0.f;
    unsigned long long m = __ballot(s);
    if (lane == 0) {
      if (cg < 3) maskA[((size_t)b*1024 + t)*4 + cg] = m;
      else maskO4[(size_t)b*1024 + t] = m;
    }
    v = s ? 0.f : v;
  }
}

DEV float simval(uint64_t mt, float nt, uint64_t msv, float ns) {
  int c = __popcll(mt & msv);
  float r = (float)c / (nt*ns + 1e-20f);
  return (r > 0.7f) ? r : 0.f;
}

// ---------------- K3: softmax col stats (max over t, sum of exp) ----------------
__global__ void adjstats_kernel(const uint64_t* __restrict__ maskO4,
                                float* __restrict__ cmax, float* __restrict__ csum)
{ // grid (32, 16) x 256
  __shared__ uint64_t ms[1024]; __shared__ float nr[1024];
  __shared__ float tmp[4][64];
  int b = blockIdx.x;
  for (int idx = threadIdx.x; idx < 1024; idx += 256) {
    uint64_t m = maskO4[(size_t)b*1024 + idx];
    ms[idx] = m; nr[idx] = sqrtf((float)__popcll(m));
  }
  __syncthreads();
  int sl = threadIdx.x & 63, q = threadIdx.x >> 6;
  int s = blockIdx.y*64 + sl;
  uint64_t msv = ms[s]; float ns = nr[s];
  float mx = 0.f;
  for (int ti = 0; ti < 256; ++ti) {
    int t = q*256 + ti;
    mx = fmaxf(mx, simval(ms[t], nr[t], msv, ns));
  }
  tmp[q][sl] = mx; __syncthreads();
  mx = fmaxf(fmaxf(tmp[0][sl], tmp[1][sl]), fmaxf(tmp[2][sl], tmp[3][sl]));
  __syncthreads();
  float sm = 0.f;
  for (int ti = 0; ti < 256; ++ti) {
    int t = q*256 + ti;
    sm += expf(simval(ms[t], nr[t], msv, ns) - mx);
  }
  tmp[q][sl] = sm; __syncthreads();
  if (q == 0) {
    cmax[(size_t)b*1024 + s] = mx;
    csum[(size_t)b*1024 + s] = (tmp[0][sl]+tmp[1][sl])+(tmp[2][sl]+tmp[3][sl]);
  }
}

// ---------------- K4: sup1/res1/sup3/res3 from o4 masks ----------------
__global__ void supres_kernel(const uint64_t* __restrict__ maskO4,
    const float* __restrict__ gc1_w, const float* __restrict__ rw1T, const float* __restrict__ gc1_res_b,
    const float* __restrict__ gc3_w, const float* __restrict__ rw3T, const float* __restrict__ gc3_res_b,
    float* __restrict__ sup1, float* __restrict__ res1,
    float* __restrict__ sup3, float* __restrict__ res3)
{ // grid 4096 x 256 : 8 bt x 32 j
  int bt = blockIdx.x*8 + (threadIdx.x>>5);
  int j = threadIdx.x & 31;
  uint64_t m = maskO4[bt];
  float s1 = 0.f, r1 = gc1_res_b[j], s3 = 0.f, r3 = gc3_res_b[j];
  #pragma unroll
  for (int i = 0; i < 64; ++i) {
    float bf = (float)((m>>i)&1ull);
    s1 = fmaf(bf, gc1_w[i*32+j], s1);
    r1 = fmaf(bf, rw1T[i*32+j], r1);
    s3 = fmaf(bf, gc3_w[i*32+j], s3);
    r3 = fmaf(bf, rw3T[i*32+j], r3);
  }
  size_t o = (size_t)bt*32 + j;
  sup1[o] = s1; res1[o] = r1; sup3[o] = s3; res3[o] = r3;
}

// ---------------- dis-banded matmul (W=64; tail < 1e-10 relative) ----------------
template<int RESMODE>
__global__ void dismm_kernel(const float* __restrict__ sup, const float* __restrict__ resf,
                             const uint32_t* __restrict__ resm, const float* __restrict__ dis,
                             float* __restrict__ out)
{ // grid (32, 16) x 256
  __shared__ float sl_[192][33];
  int b = blockIdx.x, t0 = blockIdx.y*64;
  for (int idx = threadIdx.x; idx < 192*32; idx += 256) {
    int r = idx>>5, j = idx&31;
    int t = t0 - 64 + r;
    sl_[r][j] = (t >= 0 && t < 1024) ? sup[((size_t)b*1024 + t)*32 + j] : 0.f;
  }
  __syncthreads();
  int tl = threadIdx.x>>2, jg = (threadIdx.x&3)*8;
  int t = t0 + tl;
  size_t obase = ((size_t)b*1024 + t)*32 + jg;
  float acc[8];
  if (RESMODE == 0) {
    #pragma unroll
    for (int u=0;u<8;++u) acc[u] = resf[obase+u];
  } else {
    uint32_t m = resm[(size_t)b*1024 + t] >> jg;
    #pragma unroll
    for (int u=0;u<8;++u) acc[u] = (float)((m>>u)&1u);
  }
  for (int d = -64; d <= 64; ++d) {
    int ad = d < 0 ? -d : d;
    float wv = dis[ad];
    int r = 64 + tl + d;
    #pragma unroll
    for (int u=0;u<8;++u) acc[u] = fmaf(wv, sl_[r][jg+u], acc[u]);
  }
  #pragma unroll
  for (int u=0;u<8;++u) out[obase+u] = acc[u];
}

// ---------------- LIF over T -> 32-bit masks (2 batches per wave) ----------------
__global__ void lif_mask32_kernel(const float* __restrict__ buf, uint32_t* __restrict__ mask,
                                  int b_start, int nb)
{
  int wid = (blockIdx.x*256 + threadIdx.x) >> 6;
  int lane = threadIdx.x & 63;
  int bend = b_start + nb;
  int b0 = b_start + wid*2;
  int b = b0 + (lane>>5);
  int bl = b < bend ? b : bend-1;
  int j = lane & 31;
  const float* p = buf + (size_t)bl*1024*32 + j;
  bool w0ok = (b0 < bend), w1ok = (b0+1 < bend);
  float v = 0.f;
  #pragma unroll 4
  for (int t = 0; t < 1024; ++t) {
    float xv = p[(size_t)t*32];
    v = lif_step(v, xv);
    bool s = (v - 1.0f) >= 0.f;
    unsigned long long m = __ballot(s);
    if (lane == 0 && w0ok) mask[(size_t)b0*1024 + t] = (uint32_t)m;
    else if (lane == 32 && w1ok) mask[(size_t)(b0+1)*1024 + t] = (uint32_t)(m >> 32);
    v = s ? 0.f : v;
  }
}

// ---------------- sup from 32-bit masks (gc2/gc4) ----------------
__global__ void sup_mask_kernel(const uint32_t* __restrict__ mask, const float* __restrict__ w,
                                float* __restrict__ out, int bt_start)
{
  int bt = bt_start + blockIdx.x*8 + (threadIdx.x>>5);
  int j = threadIdx.x & 31;
  uint32_t m = mask[bt];
  float acc = 0.f;
  #pragma unroll
  for (int i = 0; i < 32; ++i)
    acc = fmaf((float)((m>>i)&1u), w[i*32+j], acc);
  out[(size_t)bt*32 + j] = acc;
}

// ---------------- E = exp(v - colmax) materialization (per b-chunk) ----------------
__global__ void adjE_kernel(const uint64_t* __restrict__ maskO4, const float* __restrict__ cmax,
                            float* __restrict__ E, int b_start)
{ // grid (BC, 16) x 256
  __shared__ uint64_t ms[1024]; __shared__ float nr[1024];
  int b_loc = blockIdx.x; int b = b_start + b_loc;
  for (int idx = threadIdx.x; idx < 1024; idx += 256) {
    uint64_t m = maskO4[(size_t)b*1024 + idx];
    ms[idx] = m; nr[idx] = sqrtf((float)__popcll(m));
  }
  __syncthreads();
  int tl = threadIdx.x & 127, sh = threadIdx.x >> 7;
  int sbase = blockIdx.y*64 + sh*32;
  float* Eb = E + (size_t)b_loc*1024*1024;
  for (int si = 0; si < 32; ++si) {
    int s = sbase + si;
    uint64_t msv = ms[s]; float ns = nr[s];
    float mx = cmax[(size_t)b*1024 + s];
    #pragma unroll 2
    for (int tt = 0; tt < 8; ++tt) {
      int t = tt*128 + tl;
      Eb[(size_t)s*1024 + t] = expf(simval(ms[t], nr[t], msv, ns) - mx);
    }
  }
}

// ---------------- adjacency matmul: out[t] = sum_s E[s][t]*(sup[s]/csum[s]) + res ----------------
template<int RESMODE>
__global__ void adjmm_kernel(const float* __restrict__ E, const float* __restrict__ sup,
                             const float* __restrict__ csum, const float* __restrict__ resf,
                             const uint32_t* __restrict__ resm, float* __restrict__ out, int b_start)
{ // grid (BC, 16) x 256 : thread (tg 8 -> 8 t, j 32)
  __shared__ float P[256*32];
  int b_loc = blockIdx.x; int b = b_start + b_loc;
  int t0 = blockIdx.y*64;
  int j = threadIdx.x & 31, tg = threadIdx.x >> 5;
  int tb = t0 + tg*8;
  float acc[8];
  if (RESMODE == 0) {
    #pragma unroll
    for (int u=0;u<8;++u) acc[u] = resf[((size_t)b*1024 + tb + u)*32 + j];
  } else {
    #pragma unroll
    for (int u=0;u<8;++u) acc[u] = (float)((resm[(size_t)b*1024 + tb + u] >> j) & 1u);
  }
  const float* Ebase = E + (size_t)b_loc*1024*1024 + tb;
  for (int sc = 0; sc < 4; ++sc) {
    __syncthreads();
    for (int idx = threadIdx.x; idx < 256*32; idx += 256) {
      int s_l = idx>>5, jj = idx&31;
      int s = sc*256 + s_l;
      P[idx] = sup[((size_t)b*1024 + s)*32 + jj] / csum[(size_t)b*1024 + s];
    }
    __syncthreads();
    for (int s_l = 0; s_l < 256; ++s_l) {
      size_t srow = (size_t)(sc*256 + s_l)*1024;
      float4 e0 = *(const float4*)(Ebase + srow);
      float4 e1 = *(const float4*)(Ebase + srow + 4);
      float p = P[s_l*32 + j];
      acc[0] = fmaf(e0.x, p, acc[0]); acc[1] = fmaf(e0.y, p, acc[1]);
      acc[2] = fmaf(e0.z, p, acc[2]); acc[3] = fmaf(e0.w, p, acc[3]);
      acc[4] = fmaf(e1.x, p, acc[4]); acc[5] = fmaf(e1.y, p, acc[5]);
      acc[6] = fmaf(e1.z, p, acc[6]); acc[7] = fmaf(e1.w, p, acc[7]);
    }
  }
  #pragma unroll
  for (int u=0;u<8;++u) out[((size_t)b*1024 + tb + u)*32 + j] = acc[u];
}

// ---------------- linear: g_pre = [x1|x2] @ lin^T + b ----------------
__global__ void linear_kernel(const uint32_t* __restrict__ x1m, const uint32_t* __restrict__ x2m,
                              const float* __restrict__ linT, const float* __restrict__ lin_b,
                              float* __restrict__ g_pre)
{ // grid 8192 x 256 : 4 bt x 64 c
  int bt = blockIdx.x*4 + (threadIdx.x>>6), c = threadIdx.x & 63;
  uint32_t m1 = x1m[bt], m2 = x2m[bt];
  float acc = lin_b[c];
  #pragma unroll
  for (int i = 0; i < 32; ++i) acc = fmaf((float)((m1>>i)&1u), linT[i*64 + c], acc);
  #pragma unroll
  for (int i = 0; i < 32; ++i) acc = fmaf((float)((m2>>i)&1u), linT[(32+i)*64 + c], acc);
  g_pre[(size_t)bt*64 + c] = acc;
}

// ---------------- LIF over T for g (64 channels) -> maskA word 3 ----------------
__global__ void lifD_kernel(const float* __restrict__ g_pre, uint64_t* __restrict__ maskA)
{ // grid 8 x 256 : 4 b per block (1 wave each)
  int b = blockIdx.x*4 + (threadIdx.x>>6), c = threadIdx.x & 63;
  const float* p = g_pre + (size_t)b*1024*64 + c;
  float v = 0.f;
  #pragma unroll 4
  for (int t = 0; t < 1024; ++t) {
    float xv = p[(size_t)t*64];
    v = lif_step(v, xv);
    bool s = (v - 1.0f) >= 0.f;
    unsigned long long m = __ballot(s);
    if (c == 0) maskA[((size_t)b*1024 + t)*4 + 3] = m;
    v = s ? 0.f : v;
  }
}

// ---------------- tim: 1023 serial steps, LUT conv + tagged qword messages ----------------
// 256 blocks x 1 channel. msg[t][ch] = ((0x40000000+t)<<32) | batch_bitmask — data IS the
// message (single atomic qword; 0xAA poison / stale state never alias a valid tag).
// Conv over batch axis via per-i 8-entry LUT of tap-sums (built once, 8KB LDS):
// field = bits (j-1,j,j+1) of channel-i's batch mask; contribution = lut[i][field].
__global__ __launch_bounds__(256) void tim_kernel(const uint64_t* __restrict__ maskA,
    const float* __restrict__ tim_w, uint64_t* __restrict__ msg)
{
  __shared__ float lut[32*8*8];      // [ii][kk][field]
  __shared__ uint32_t chm[256];      // [channel] = prev-step batch bitmask
  __shared__ float red[32][9];       // [j][kk] partials
  const int tid = threadIdx.x;
  const int f = blockIdx.x;
  const int j = tid & 31, kk = tid >> 5;   // j = batch, kk = i-chunk (32 i's each)
  // build LUT: thread handles i = tid
  {
    int i = tid;
    const float* wr = tim_w + ((size_t)f*256 + i)*3;
    float w0 = wr[0], w1 = wr[1], w2 = wr[2];
    float* lp = &lut[((i & 31)*8 + (i >> 5))*8];
    #pragma unroll
    for (int fd = 0; fd < 8; ++fd)
      lp[fd] = ((fd&1)?w0:0.f) + ((fd&2)?w1:0.f) + ((fd&4)?w2:0.f);
  }
  float v_in = 0.f, v_out = 0.f;
  // t=0 publish: input spikes for this channel (lanes 0..31 = batches)
  if (tid < 32) {
    uint64_t mw = maskA[((size_t)tid*1024 + 0)*4 + (f>>6)];
    bool bit = (mw >> (f&63)) & 1ull;
    unsigned long long bal = __ballot(bit);
    if (tid == 0) {
      uint64_t tag = ((uint64_t)0x40000000u) << 32;
      __hip_atomic_store(&msg[f], tag | (uint32_t)bal, __ATOMIC_RELAXED, __HIP_MEMORY_SCOPE_AGENT);
    }
  }
  __syncthreads();   // lut ready

  const int lbase = kk*8;  // float offset of [.][kk][0] within a 64-float ii-row
  for (int t = 1; t < 1024; ++t) {
    // hoisted xi load (latency hides under the poll)
    uint64_t mw = 0;
    if (tid < 32) mw = maskA[((size_t)tid*1024 + t)*4 + (f>>6)];
    // poll: thread c waits for msg[t-1][c]
    {
      uint32_t exp_tag = 0x40000000u + (uint32_t)(t-1);
      const uint64_t* src = &msg[(size_t)(t-1)*256 + tid];
      for (;;) {
        uint64_t q = __hip_atomic_load(src, __ATOMIC_RELAXED, __HIP_MEMORY_SCOPE_AGENT);
        if ((uint32_t)(q >> 32) == exp_tag) { chm[tid] = (uint32_t)q; break; }
        __builtin_amdgcn_s_sleep(1);
      }
    }
    __syncthreads();
    // conv partials via LUT: thread (kk, j) covers i in [kk*32, kk*32+32)
    float a0=0.f, a1=0.f, a2=0.f, a3=0.f;
    #pragma unroll
    for (int ii = 0; ii < 32; ii += 4) {
      uint32_t fd0 = (uint32_t)(((((uint64_t)chm[kk*32 + ii+0]) << 1) >> j)) & 7u;
      uint32_t fd1 = (uint32_t)(((((uint64_t)chm[kk*32 + ii+1]) << 1) >> j)) & 7u;
      uint32_t fd2 = (uint32_t)(((((uint64_t)chm[kk*32 + ii+2]) << 1) >> j)) & 7u;
      uint32_t fd3 = (uint32_t)(((((uint64_t)chm[kk*32 + ii+3]) << 1) >> j)) & 7u;
      a0 += lut[(ii+0)*64 + lbase + fd0];
      a1 += lut[(ii+1)*64 + lbase + fd1];
      a2 += lut[(ii+2)*64 + lbase + fd2];
      a3 += lut[(ii+3)*64 + lbase + fd3];
    }
    red[j][kk] = (a0 + a1) + (a2 + a3);
    __syncthreads();
    if (tid < 32) {
      const float* rp = &red[j][0];
      float xc = rp[0];
      #pragma unroll
      for (int u=1;u<8;++u) xc += rp[u];
      v_in = lif_step(v_in, xc);
      bool s_in = (v_in - 0.3f) >= 0.f;
      v_in = s_in ? 0.f : v_in;
      float xi = (float)((mw >> (f&63)) & 1ull);
      float xmix = (s_in ? 1.f : 0.f)*0.6f + xi*0.4f;
      v_out = lif_step(v_out, xmix);
      bool s_out = (v_out - 0.5f) >= 0.f;
      v_out = s_out ? 0.f : v_out;
      unsigned long long bal = __ballot(s_out);
      if (tid == 0) {
        uint64_t tag = ((uint64_t)(0x40000000u + (uint32_t)t)) << 32;
        __hip_atomic_store(&msg[(size_t)t*256 + f], tag | (uint32_t)bal,
                           __ATOMIC_RELAXED, __HIP_MEMORY_SCOPE_AGENT);
      }
    }
  }
}

// ---------------- final: h = spike + residual; scores = sigmoid(h @ cls^T + b) ----------------
__global__ void final_kernel(const uint64_t* __restrict__ msg, const float* __restrict__ x,
                             const float* __restrict__ cls_w, const float* __restrict__ cls_b,
                             float* __restrict__ out)
{ // grid 32768 x 256 : one (b,t) per block
  __shared__ float wsum[4];
  int bt = blockIdx.x; int b = bt>>10, t = bt&1023;
  int f = threadIdx.x;
  uint32_t cm = (uint32_t)msg[(size_t)t*256 + f];
  float ho = (float)((cm >> b) & 1u) + x[(size_t)bt*256 + f];
  out[(size_t)bt*256 + f] = ho;
  float p = ho * cls_w[f];
  #pragma unroll
  for (int o = 32; o > 0; o >>= 1) p += __shfl_down(p, o);
  if ((threadIdx.x & 63) == 0) wsum[threadIdx.x>>6] = p;
  __syncthreads();
  if (threadIdx.x == 0) {
    float z = ((wsum[0]+wsum[1])+(wsum[2]+wsum[3])) + cls_b[0];
    float sc;
    if (z >= 0.f) sc = 1.f/(1.f + expf(-z));
    else { float e = expf(z); sc = e/(1.f + e); }
    out[8388608u + (size_t)bt] = sc;
  }
}

// ---------------- host launch ----------------
extern "C" void kernel_launch(void* const* d_in, const int* in_sizes, int n_in,
                              void* d_out, int out_size, void* d_ws, size_t ws_size,
                              hipStream_t stream) {
  (void)in_sizes; (void)n_in; (void)out_size; (void)ws_size;
  const float* x        = (const float*)d_in[0];
  const float* convs_w  = (const float*)d_in[1];
  const float* convs_b  = (const float*)d_in[2];
  const float* bn_g     = (const float*)d_in[3];
  const float* bn_b     = (const float*)d_in[4];
  const float* bn_m     = (const float*)d_in[5];
  const float* bn_v     = (const float*)d_in[6];
  const float* conv4_w  = (const float*)d_in[7];
  const float* gc1_w    = (const float*)d_in[8];
  const float* gc1_rw   = (const float*)d_in[9];
  const float* gc1_rb   = (const float*)d_in[10];
  const float* gc2_w    = (const float*)d_in[11];
  const float* gc3_w    = (const float*)d_in[12];
  const float* gc3_rw   = (const float*)d_in[13];
  const float* gc3_rb   = (const float*)d_in[14];
  const float* gc4_w    = (const float*)d_in[15];
  const float* lin_w    = (const float*)d_in[16];
  const float* lin_b    = (const float*)d_in[17];
  const float* tim_w    = (const float*)d_in[18];
  const float* cls_w    = (const float*)d_in[19];
  const float* cls_b    = (const float*)d_in[20];

  char* ws = (char*)d_ws;
  float* prm      = (float*)(ws + OFF_PRM);
  float* dis      = (float*)(ws + OFF_DIS);
  float* rw1T     = (float*)(ws + OFF_RW1T);
  float* rw3T     = (float*)(ws + OFF_RW3T);
  float* linT     = (float*)(ws + OFF_LINT);
  float* wT       = (float*)(ws + OFF_WT);
  float* preact   = (float*)(ws + OFF_PRE);
  uint64_t* maskA = (uint64_t*)(ws + OFF_MASKA);
  uint64_t* maskO4= (uint64_t*)(ws + OFF_MASKO4);
  float* cmax     = (float*)(ws + OFF_CMAX);
  float* csum     = (float*)(ws + OFF_CSUM);
  float* sup1     = (float*)(ws + OFF_SUP1);
  float* res1     = (float*)(ws + OFF_RES1);
  float* sup3     = (float*)(ws + OFF_SUP3);
  float* res3     = (float*)(ws + OFF_RES3);
  uint32_t* x1h   = (uint32_t*)(ws + OFF_X1H);
  uint32_t* x2h   = (uint32_t*)(ws + OFF_X2H);
  uint32_t* x1m   = (uint32_t*)(ws + OFF_X1M);
  uint32_t* x2m   = (uint32_t*)(ws + OFF_X2M);
  float* g_pre    = (float*)(ws + OFF_GPRE);
  uint64_t* msg   = (uint64_t*)(ws + OFF_MSG);
  float* E        = (float*)(ws + OFF_PRE);   // aliases preact (dead after lifA)

  const int BC = 8;   // E chunk = 8 batches x 4MB = 32MB, exactly the preact region

  prep_kernel<<<805, 256, 0, stream>>>(convs_w, convs_b, bn_g, bn_b, bn_m, bn_v, conv4_w,
                                       gc1_rw, gc3_rw, lin_w,
                                       wT, prm, dis, rw1T, rw3T, linT);
  conv_kernel<<<dim3(16, 32), 256, 0, stream>>>(x, wT, prm, preact);
  lifA_kernel<<<32, 256, 0, stream>>>(preact, maskA, maskO4);
  adjstats_kernel<<<dim3(32, 16), 256, 0, stream>>>(maskO4, cmax, csum);
  supres_kernel<<<4096, 256, 0, stream>>>(maskO4, gc1_w, rw1T, gc1_rb, gc3_w, rw3T, gc3_rb,
                                          sup1, res1, sup3, res3);
  // dis path (full B)
  dismm_kernel<0><<<dim3(32, 16), 256, 0, stream>>>(sup3, res3, nullptr, dis, res3);
  lif_mask32_kernel<<<4, 256, 0, stream>>>(res3, x2h, 0, 32);
  sup_mask_kernel<<<4096, 256, 0, stream>>>(x2h, gc4_w, sup3, 0);
  dismm_kernel<1><<<dim3(32, 16), 256, 0, stream>>>(sup3, nullptr, x2h, dis, res3);
  lif_mask32_kernel<<<4, 256, 0, stream>>>(res3, x2m, 0, 32);
  // adj path, chunked over batches (E = 32MB aliasing preact)
  for (int cs = 0; cs < 32; cs += BC) {
    adjE_kernel<<<dim3(BC, 16), 256, 0, stream>>>(maskO4, cmax, E, cs);
    adjmm_kernel<0><<<dim3(BC, 16), 256, 0, stream>>>(E, sup1, csum, res1, nullptr, res1, cs);
    lif_mask32_kernel<<<1, 256, 0, stream>>>(res1, x1h, cs, BC);
    sup_mask_kernel<<<BC*128, 256, 0, stream>>>(x1h, gc2_w, sup1, cs*1024);
    adjmm_kernel<1><<<dim3(BC, 16), 256, 0, stream>>>(E, sup1, csum, nullptr, x1h, res1, cs);
    lif_mask32_kernel<<<1, 256, 0, stream>>>(res1, x1m, cs, BC);
  }
  linear_kernel<<<8192, 256, 0, stream>>>(x1m, x2m, linT, lin_b, g_pre);
  lifD_kernel<<<8, 256, 0, stream>>>(g_pre, maskA);
  tim_kernel<<<256, 256, 0, stream>>>(maskA, tim_w, msg);
  final_kernel<<<32768, 256, 0, stream>>>(msg, x, cls_w, cls_b, (float*)d_out);
}